// Round 5
// baseline (105.262 us; speedup 1.0000x reference)
//
#include <hip/hip_runtime.h>
#include <hip/hip_bf16.h>

// Fixed shape: B=4096, I=1024, H=1024
#define B_ROWS 4096
#define H_DIM  1024
#define K_DIM  2048   // I + H
#define N_DIM  4096   // 4H
#define NT32   64     // K_DIM / 32 K-tiles

typedef __attribute__((ext_vector_type(8))) short bf16x8;
typedef __attribute__((ext_vector_type(4))) float f32x4;

__device__ __forceinline__ unsigned short f2bf(float f) {
  union { float f; unsigned int u; } v; v.f = f;
  unsigned int u = v.u;
  return (unsigned short)((u + 0x7fffu + ((u >> 16) & 1u)) >> 16);
}
__device__ __forceinline__ float bf2f(unsigned short u) {
  union { unsigned int u; float f; } v; v.u = ((unsigned int)u) << 16;
  return v.f;
}

__device__ __forceinline__ void gload_lds16(const void* g, void* l) {
  __builtin_amdgcn_global_load_lds(
      (const __attribute__((address_space(1))) void*)g,
      (__attribute__((address_space(3))) void*)l, 16, 0, 0);
}

// -------- merged pack kernel: fp32 -> bf16 for A=concat(x,h) and W ---------
__global__ __launch_bounds__(256) void pack_kernel(
    const float* __restrict__ x, const float* __restrict__ h,
    const float* __restrict__ W, unsigned short* __restrict__ Abf,
    unsigned short* __restrict__ Wbf) {
  int bid = blockIdx.x;
  if (bid < 8192) {
    int t = bid * 256 + threadIdx.x;
    int e = t * 4;
    int row = e >> 11;
    int col = e & 2047;
    const float* src = (col < 1024) ? (x + (size_t)row * 1024 + col)
                                    : (h + (size_t)row * 1024 + (col - 1024));
    float4 v = *(const float4*)src;
    ushort4 o;
    o.x = f2bf(v.x); o.y = f2bf(v.y); o.z = f2bf(v.z); o.w = f2bf(v.w);
    *(ushort4*)(Abf + e) = o;
  } else {
    int t = (bid - 8192) * 256 + threadIdx.x;
    int e = t * 4;
    float4 v = *(const float4*)(W + e);
    ushort4 o;
    o.x = f2bf(v.x); o.y = f2bf(v.y); o.z = f2bf(v.z); o.w = f2bf(v.w);
    *(ushort4*)(Wbf + e) = o;
  }
}

// -------- GEMM: 256x256 tile, BK=32, 4-LDS-buffer, 1 barrier / K-tile ------
// gates(bf16) = A(4096x2048 bf16) * W^T(4096x2048 bf16) + bias(fp32)
// 8 waves = 2(M) x 4(N); per-wave 128x64 output. LDS = 4 x 32KB buffers
// (buf = A 16KB + B 16KB, 16x32-bf16 subtiles of 1KB, st_16x32 swizzle via
// pre-swizzled global source + swizzled ds_read).
// Pipeline per K-tile t: stage(t+3) -> vmcnt(8) -> barrier -> read frags(t+1)
// -> lgkmcnt(12) -> 32 MFMA on frags(t). Register frags double-buffered P/Q.
// Safety: wave skew bounded by 1 barrier; staging writes buf[(t+3)&3] which
// no wave can still be reading (reads of buf[X] end 2+ barriers earlier).

#define UNR _Pragma("unroll")

#define TILE1(tt, BUF, FRa, FRb, FWa, FWb)                                   \
  {                                                                          \
    const int kt3 = ((tt) + 3) & (NT32 - 1);                                 \
    char* const Ld = lds + (((BUF) + 3) & 3) * 32768;                        \
    const unsigned short* pA = gAw + ((size_t)kt3 << 5);                     \
    const unsigned short* pB = gBw + ((size_t)kt3 << 5);                     \
    gload_lds16(pA, Ld + dstOfs);                                            \
    gload_lds16(pA + 16 * K_DIM, Ld + dstOfs + 1024);                        \
    gload_lds16(pB, Ld + 16384 + dstOfs);                                    \
    gload_lds16(pB + 16 * K_DIM, Ld + 16384 + dstOfs + 1024);                \
    asm volatile("s_waitcnt vmcnt(8)" ::: "memory");                         \
    __builtin_amdgcn_s_barrier();                                            \
    const char* const Ln = lds + (((BUF) + 1) & 3) * 32768;                  \
    UNR for (int mi = 0; mi < 8; ++mi)                                       \
      FWa[mi] = *(const bf16x8*)(Ln + (wm * 8 + mi) * 1024 + lofs);          \
    UNR for (int ni = 0; ni < 4; ++ni)                                       \
      FWb[ni] = *(const bf16x8*)(Ln + 16384 + (wn * 4 + ni) * 1024 + lofs);  \
    asm volatile("s_waitcnt lgkmcnt(12)" ::: "memory");                      \
    __builtin_amdgcn_sched_barrier(0);                                       \
    __builtin_amdgcn_s_setprio(1);                                           \
    UNR for (int mi = 0; mi < 8; ++mi)                                       \
      UNR for (int ni = 0; ni < 4; ++ni)                                     \
        acc[mi][ni] = __builtin_amdgcn_mfma_f32_16x16x32_bf16(               \
            FRa[mi], FRb[ni], acc[mi][ni], 0, 0, 0);                         \
    __builtin_amdgcn_s_setprio(0);                                           \
  }

#define PSTAGE(kt, BUFOFS)                                                   \
  {                                                                          \
    const unsigned short* pA = gAw + ((size_t)(kt) << 5);                    \
    const unsigned short* pB = gBw + ((size_t)(kt) << 5);                    \
    char* const Ld = lds + (BUFOFS);                                         \
    gload_lds16(pA, Ld + dstOfs);                                            \
    gload_lds16(pA + 16 * K_DIM, Ld + dstOfs + 1024);                        \
    gload_lds16(pB, Ld + 16384 + dstOfs);                                    \
    gload_lds16(pB + 16 * K_DIM, Ld + 16384 + dstOfs + 1024);                \
  }

__global__ __launch_bounds__(512, 2) void gemm_kernel(
    const unsigned short* __restrict__ A, const unsigned short* __restrict__ W,
    const float* __restrict__ bias, unsigned short* __restrict__ C) {
  __shared__ __align__(16) char lds[131072];

  const int tid = threadIdx.x;
  const int w = tid >> 6, l = tid & 63;
  const int wm = w >> 2, wn = w & 3;            // 2 x 4 wave grid

  // XCD-aware swizzle: 256 blocks, 8 XCDs, each XCD owns a 4x8 rect.
  const int bid = blockIdx.x;
  const int xcd = bid & 7, li = bid >> 3;
  const int by = (xcd & 3) * 4 + (li >> 3);
  const int bx = ((xcd >> 2) << 3) + (li & 7);
  const int bm = by * 256, bn = bx * 256;

  // swizzled ds_read lane offset within a 1KB subtile (16 rows x 32 bf16)
  const int lofs = (((l & 15) * 64) + ((l >> 4) * 16)) ^ ((l & 8) << 2);
  // inverse-swizzle lane mapping for linear global_load_lds staging
  const int lane_r = (l >> 2) & 15;
  const int lane_c = ((l & 3) * 8) ^ (((l >> 5) & 1) * 16);

  // wave w stages A rows 32w..32w+31 and B rows 32w..32w+31 (two 1KB subtiles each)
  const int dstOfs = w * 2048;
  const unsigned short* gAw = A + (size_t)(bm + 32 * w + lane_r) * K_DIM + lane_c;
  const unsigned short* gBw = W + (size_t)(bn + 32 * w + lane_r) * K_DIM + lane_c;

  f32x4 acc[8][4];
#pragma unroll
  for (int i = 0; i < 8; ++i)
#pragma unroll
    for (int j = 0; j < 4; ++j) acc[i][j] = (f32x4)0.0f;

  // ---- prologue: stage tiles 0,1,2 into buf 0,1,2 ----
  PSTAGE(0, 0);
  PSTAGE(1, 32768);
  PSTAGE(2, 65536);
  asm volatile("s_waitcnt vmcnt(8)" ::: "memory");   // tile0 landed
  __builtin_amdgcn_s_barrier();

  bf16x8 aP[8], bP[4], aQ[8], bQ[4];
#pragma unroll
  for (int mi = 0; mi < 8; ++mi)
    aP[mi] = *(const bf16x8*)(lds + (wm * 8 + mi) * 1024 + lofs);
#pragma unroll
  for (int ni = 0; ni < 4; ++ni)
    bP[ni] = *(const bf16x8*)(lds + 16384 + (wn * 4 + ni) * 1024 + lofs);

  for (int t = 0; t < NT32; t += 4) {
    TILE1(t + 0, 0, aP, bP, aQ, bQ);
    TILE1(t + 1, 1, aQ, bQ, aP, bP);
    TILE1(t + 2, 2, aP, bP, aQ, bQ);
    TILE1(t + 3, 3, aQ, bQ, aP, bP);
  }

  // ---- epilogue: +bias (fp32), convert to bf16, store ----
  const int lm = l & 15, lq = l >> 4;
  float bv[4];
#pragma unroll
  for (int ni = 0; ni < 4; ++ni) bv[ni] = bias[bn + wn * 64 + ni * 16 + lm];
  unsigned short* Cb = C + (size_t)(bm + wm * 128) * N_DIM + bn + wn * 64;
#pragma unroll
  for (int mi = 0; mi < 8; ++mi)
#pragma unroll
    for (int j = 0; j < 4; ++j) {
      const size_t rofs = (size_t)(mi * 16 + lq * 4 + j) * N_DIM;
#pragma unroll
      for (int ni = 0; ni < 4; ++ni)
        Cb[rofs + ni * 16 + lm] = f2bf(acc[mi][ni][j] + bv[ni]);
    }
}

// -------- fused LN + activations + cell update -----------------------------
__device__ __forceinline__ float2 blk_sum2(float s, float q, float* red,
                                           int wid, int lane) {
#pragma unroll
  for (int o = 32; o >= 1; o >>= 1) {
    s += __shfl_xor(s, o, 64);
    q += __shfl_xor(q, o, 64);
  }
  __syncthreads();
  if (lane == 0) { red[wid * 2] = s; red[wid * 2 + 1] = q; }
  __syncthreads();
  s = red[0] + red[2] + red[4] + red[6];
  q = red[1] + red[3] + red[5] + red[7];
  return make_float2(s, q);
}

__device__ __forceinline__ float sigmoidf_(float x) {
  return 1.0f / (1.0f + __expf(-x));
}
__device__ __forceinline__ float tanhf_(float x) {
  return 1.0f - 2.0f / (__expf(2.0f * x) + 1.0f);
}

__global__ __launch_bounds__(256) void ln_lstm_kernel(
    const unsigned short* __restrict__ gates, const float* __restrict__ cprev,
    const float* __restrict__ g_i, const float* __restrict__ b_i,
    const float* __restrict__ g_f, const float* __restrict__ b_f,
    const float* __restrict__ g_g, const float* __restrict__ b_g,
    const float* __restrict__ g_o, const float* __restrict__ b_o,
    const float* __restrict__ g_c, const float* __restrict__ b_c,
    float* __restrict__ out) {
  const int b = blockIdx.x;
  const int t = threadIdx.x;
  const int wid = t >> 6, lane = t & 63;
  __shared__ float red[8];

  const unsigned short* grow = gates + (size_t)b * N_DIM;
  const int c0 = t * 4;

  float v[4][4];
#pragma unroll
  for (int g = 0; g < 4; g++) {
    ushort4 raw = *(const ushort4*)(grow + g * 1024 + c0);
    v[g][0] = bf2f(raw.x); v[g][1] = bf2f(raw.y);
    v[g][2] = bf2f(raw.z); v[g][3] = bf2f(raw.w);
  }

  const float4 gamma[4] = {*(const float4*)(g_i + c0), *(const float4*)(g_f + c0),
                           *(const float4*)(g_g + c0), *(const float4*)(g_o + c0)};
  const float4 beta[4]  = {*(const float4*)(b_i + c0), *(const float4*)(b_f + c0),
                           *(const float4*)(b_g + c0), *(const float4*)(b_o + c0)};

  float a[4][4];
#pragma unroll
  for (int g = 0; g < 4; g++) {
    float s = v[g][0] + v[g][1] + v[g][2] + v[g][3];
    float q = v[g][0]*v[g][0] + v[g][1]*v[g][1] + v[g][2]*v[g][2] + v[g][3]*v[g][3];
    float2 r = blk_sum2(s, q, red, wid, lane);
    float mu = r.x * (1.0f / 1024.0f);
    float var = r.y * (1.0f / 1024.0f) - mu * mu;
    float inv = rsqrtf(var + 1e-5f);
    const float* gm = (const float*)&gamma[g];
    const float* bt = (const float*)&beta[g];
#pragma unroll
    for (int j = 0; j < 4; j++) {
      float n = (v[g][j] - mu) * inv * gm[j] + bt[j];
      a[g][j] = (g == 2) ? tanhf_(n) : sigmoidf_(n);
    }
  }

  float4 cp = *(const float4*)(cprev + (size_t)b * 1024 + c0);
  const float* cpe = (const float*)&cp;
  float cn[4];
#pragma unroll
  for (int j = 0; j < 4; j++)
    cn[j] = a[1][j] * cpe[j] + a[0][j] * a[2][j];

  {
    float s = cn[0] + cn[1] + cn[2] + cn[3];
    float q = cn[0]*cn[0] + cn[1]*cn[1] + cn[2]*cn[2] + cn[3]*cn[3];
    float2 r = blk_sum2(s, q, red, wid, lane);
    float mu = r.x * (1.0f / 1024.0f);
    float var = r.y * (1.0f / 1024.0f) - mu * mu;
    float inv = rsqrtf(var + 1e-5f);
    float4 gm = *(const float4*)(g_c + c0);
    float4 bt = *(const float4*)(b_c + c0);
    const float* gme = (const float*)&gm;
    const float* bte = (const float*)&bt;
    float hn[4];
#pragma unroll
    for (int j = 0; j < 4; j++) {
      float n = (cn[j] - mu) * inv * gme[j] + bte[j];
      hn[j] = a[3][j] * tanhf_(n);
    }
    *(float4*)(out + (size_t)b * 1024 + c0) = make_float4(hn[0], hn[1], hn[2], hn[3]);
    *(float4*)(out + (size_t)B_ROWS * H_DIM + (size_t)b * 1024 + c0) =
        make_float4(cn[0], cn[1], cn[2], cn[3]);
  }
}

// ---------------------------------------------------------------------------
extern "C" void kernel_launch(void* const* d_in, const int* in_sizes, int n_in,
                              void* d_out, int out_size, void* d_ws,
                              size_t ws_size, hipStream_t stream) {
  const float* x    = (const float*)d_in[0];
  const float* h    = (const float*)d_in[1];
  const float* c    = (const float*)d_in[2];
  const float* W    = (const float*)d_in[3];
  const float* bias = (const float*)d_in[4];
  const float* ln_i_g = (const float*)d_in[5];
  const float* ln_i_b = (const float*)d_in[6];
  const float* ln_f_g = (const float*)d_in[7];
  const float* ln_f_b = (const float*)d_in[8];
  const float* ln_g_g = (const float*)d_in[9];
  const float* ln_g_b = (const float*)d_in[10];
  const float* ln_o_g = (const float*)d_in[11];
  const float* ln_o_b = (const float*)d_in[12];
  const float* ln_c_g = (const float*)d_in[13];
  const float* ln_c_b = (const float*)d_in[14];

  // workspace: A_bf16 (16MB) | W_bf16 (16MB) | gates bf16 (32MB)
  unsigned short* Abf = (unsigned short*)d_ws;
  unsigned short* Wbf = Abf + (size_t)B_ROWS * K_DIM;
  unsigned short* gates = Wbf + (size_t)N_DIM * K_DIM;

  pack_kernel<<<16384, 256, 0, stream>>>(x, h, W, Abf, Wbf);

  dim3 ggrid(256);
  gemm_kernel<<<ggrid, 512, 0, stream>>>(Abf, Wbf, bias, gates);

  ln_lstm_kernel<<<B_ROWS, 256, 0, stream>>>(
      gates, c, ln_i_g, ln_i_b, ln_f_g, ln_f_b, ln_g_g, ln_g_b,
      ln_o_g, ln_o_b, ln_c_g, ln_c_b, (float*)d_out);
}